// Round 1
// baseline (4397.909 us; speedup 1.0000x reference)
//
#include <hip/hip_runtime.h>
#include <hip/hip_bf16.h>

#define TPB 256

__device__ __forceinline__ float fsigmoid(float x) {
  return __builtin_amdgcn_rcpf(1.0f + __expf(-x));
}
__device__ __forceinline__ float fsilu(float x) { return x * fsigmoid(x); }

// W2T[l][k][m] = eW2[l][m][k]  (so column k of eW2 is a contiguous row -> s_load)
__global__ void w2_transpose_kernel(const float* __restrict__ eW2, float* __restrict__ W2T) {
  int t = blockIdx.x * 256 + threadIdx.x;
  if (t < 2 * 64 * 64) {
    int l = t >> 12, k = (t >> 6) & 63, m = t & 63;
    W2T[t] = eW2[(l << 12) + (m << 6) + k];
  }
}

__launch_bounds__(TPB, 2)
__global__ void gnn_kernel(
    const float* __restrict__ X, const float* __restrict__ CTX,
    const float* __restrict__ EW1, const float* __restrict__ EB1,
    const float* __restrict__ EB2,
    const float* __restrict__ GW, const float* __restrict__ GB,
    const float* __restrict__ LNG, const float* __restrict__ LNB,
    const float* __restrict__ NW1, const float* __restrict__ NB1,
    const float* __restrict__ NW2, const float* __restrict__ NB2,
    const float* __restrict__ HW1, const float* __restrict__ HB1,
    const float* __restrict__ HW2, const float* __restrict__ HB2,
    const float* __restrict__ W2T, float* __restrict__ OUTP)
{
  __shared__ float sz[29 * 24];      // z, stride 24
  __shared__ float spi[29 * 66];     // pi (+eb1); later zn (rows d<22)
  __shared__ float spj[29 * 66];     // pj; later h1
  __shared__ float smacc[29 * 66];   // aggregated m_i
  __shared__ float szm[24];
  __shared__ float shh[64];
  __shared__ float sob[24];

  const int b = blockIdx.x;
  const int tid = threadIdx.x;
  const int lane = tid & 63;
  const int wave = tid >> 6;

  // ---- load z = concat(x, context): [29][22]
  for (int t = tid; t < 29 * 22; t += TPB) {
    int i = t / 22, d = t - i * 22;
    float v = (d < 6) ? X[b * 174 + i * 6 + d] : CTX[b * 464 + i * 16 + (d - 6)];
    sz[i * 24 + d] = v;
  }
  __syncthreads();

  #pragma unroll 1
  for (int l = 0; l < 2; ++l) {
    // ---- phase 1: pi = z@eW1[:22] + eb1 ; pj = z@eW1[22:] ; zero macc
    {
      const float* W1 = EW1 + l * (44 * 64);
      float wpi[22], wpj[22];
      #pragma unroll
      for (int d = 0; d < 22; ++d) {
        wpi[d] = W1[d * 64 + lane];
        wpj[d] = W1[(22 + d) * 64 + lane];
      }
      float be1 = EB1[l * 64 + lane];
      for (int i = wave; i < 29; i += 4) {
        float a = be1, c = 0.f;
        #pragma unroll
        for (int d = 0; d < 22; ++d) {
          float zd = sz[i * 24 + d];
          a += zd * wpi[d];
          c += zd * wpj[d];
        }
        spi[i * 66 + lane] = a;
        spj[i * 66 + lane] = c;
      }
      for (int t = tid; t < 29 * 66; t += TPB) smacc[t] = 0.f;
    }
    __syncthreads();

    // ---- edges: for each (i,j): m1=silu(pi[i]+pj[j]); m2=silu(m1@eW2+eb2);
    //      g=sigmoid(m2.gW+gb); macc[i] += m2*g
    {
      const float* wt  = W2T + (l << 12);
      const float* eb2 = EB2 + l * 64;
      const float* gw  = GW + l * 64;
      const float  gb  = GB[l];
      #pragma unroll 1
      for (int it = 0; it < 4; ++it) {
        int e = 4 * tid + it;
        if (e < 841) {
          int i = e / 29;
          int j = e - i * 29;
          float m1[64];
          {
            const float2* pr = (const float2*)&spi[i * 66];
            const float2* qr = (const float2*)&spj[j * 66];
            #pragma unroll
            for (int m = 0; m < 32; ++m) {
              float2 p = pr[m], q = qr[m];
              m1[2 * m]     = fsilu(p.x + q.x);
              m1[2 * m + 1] = fsilu(p.y + q.y);
            }
          }
          float m2[64];
          float gacc = gb;
          #pragma unroll
          for (int k = 0; k < 64; ++k) {
            const float* wr = wt + (k << 6);   // uniform address -> s_load stream
            float a0 = 0.f, a1 = 0.f, a2 = 0.f, a3 = 0.f;
            #pragma unroll
            for (int m = 0; m < 64; m += 4) {
              a0 += m1[m]     * wr[m];
              a1 += m1[m + 1] * wr[m + 1];
              a2 += m1[m + 2] * wr[m + 2];
              a3 += m1[m + 3] * wr[m + 3];
            }
            float a = fsilu(((a0 + a1) + (a2 + a3)) + eb2[k]);
            m2[k] = a;
            gacc += a * gw[k];
          }
          float g = fsigmoid(gacc);
          #pragma unroll
          for (int k = 0; k < 64; ++k) {
            unsafeAtomicAdd(&smacc[i * 66 + k], m2[k] * g);
          }
        }
      }
    }
    __syncthreads();

    // ---- layernorm(z) -> spi rows [i][d<22]
    if (tid < 29) {
      float mu = 0.f;
      #pragma unroll
      for (int d = 0; d < 22; ++d) mu += sz[tid * 24 + d];
      mu *= (1.f / 22.f);
      float var = 0.f;
      #pragma unroll
      for (int d = 0; d < 22; ++d) { float dz = sz[tid * 24 + d] - mu; var += dz * dz; }
      var *= (1.f / 22.f);
      float r = rsqrtf(var + 1e-5f);
      #pragma unroll
      for (int d = 0; d < 22; ++d)
        spi[tid * 66 + d] = (sz[tid * 24 + d] - mu) * r * LNG[l * 22 + d] + LNB[l * 22 + d];
    }
    __syncthreads();

    // ---- h1 = silu([zn, macc] @ nW1 + nb1) -> spj
    {
      const float* W1 = NW1 + l * (86 * 64);
      float wa[22], wb[64];
      #pragma unroll
      for (int d = 0; d < 22; ++d) wa[d] = W1[d * 64 + lane];
      #pragma unroll
      for (int m = 0; m < 64; ++m) wb[m] = W1[(22 + m) * 64 + lane];
      float bn = NB1[l * 64 + lane];
      for (int i = wave; i < 29; i += 4) {
        float a = bn;
        #pragma unroll
        for (int d = 0; d < 22; ++d) a += spi[i * 66 + d] * wa[d];
        #pragma unroll
        for (int m = 0; m < 64; ++m) a += smacc[i * 66 + m] * wb[m];
        spj[i * 66 + lane] = fsilu(a);
      }
    }
    __syncthreads();

    // ---- h2 = h1 @ nW2 + nb2 ; z += h2
    {
      const float* W2 = NW2 + l * (64 * 22);
      const float* b2 = NB2 + l * 22;
      for (int t = tid; t < 29 * 22; t += TPB) {
        int i = t / 22, d = t - i * 22;
        float a = b2[d];
        #pragma unroll
        for (int m = 0; m < 64; ++m) a += spj[i * 66 + m] * W2[m * 22 + d];
        sz[i * 24 + d] += a;
      }
    }
    __syncthreads();
  }

  // ---- head: mean-pool, relu MLP, pad-write
  if (tid < 22) {
    float s = 0.f;
    #pragma unroll
    for (int i = 0; i < 29; ++i) s += sz[i * 24 + tid];
    szm[tid] = s * (1.f / 29.f);
  }
  __syncthreads();
  if (tid < 64) {
    float a = HB1[tid];
    #pragma unroll
    for (int d = 0; d < 22; ++d) a += szm[d] * HW1[d * 64 + tid];
    shh[tid] = fmaxf(a, 0.f);
  }
  __syncthreads();
  if (tid < 24) {
    float a = HB2[tid];
    #pragma unroll
    for (int m = 0; m < 64; ++m) a += shh[m] * HW2[m * 24 + tid];
    sob[tid] = a;
  }
  __syncthreads();
  for (int t = tid; t < 29 * 12; t += TPB) {
    OUTP[b * 348 + t] = (t < 24) ? sob[t] : 0.f;
  }
}

extern "C" void kernel_launch(void* const* d_in, const int* in_sizes, int n_in,
                              void* d_out, int out_size, void* d_ws, size_t ws_size,
                              hipStream_t stream) {
  const float* X   = (const float*)d_in[0];
  const float* CTX = (const float*)d_in[1];
  const float* EW1 = (const float*)d_in[2];
  const float* EB1 = (const float*)d_in[3];
  const float* EW2 = (const float*)d_in[4];
  const float* EB2 = (const float*)d_in[5];
  const float* GW  = (const float*)d_in[6];
  const float* GB  = (const float*)d_in[7];
  const float* LNG = (const float*)d_in[8];
  const float* LNB = (const float*)d_in[9];
  const float* NW1 = (const float*)d_in[10];
  const float* NB1 = (const float*)d_in[11];
  const float* NW2 = (const float*)d_in[12];
  const float* NB2 = (const float*)d_in[13];
  const float* HW1 = (const float*)d_in[14];
  const float* HB1 = (const float*)d_in[15];
  const float* HW2 = (const float*)d_in[16];
  const float* HB2 = (const float*)d_in[17];
  float* OUTP = (float*)d_out;
  float* W2T  = (float*)d_ws;   // 2*64*64 floats = 32 KB scratch

  hipLaunchKernelGGL(w2_transpose_kernel, dim3(32), dim3(256), 0, stream, EW2, W2T);
  hipLaunchKernelGGL(gnn_kernel, dim3(4096), dim3(TPB), 0, stream,
                     X, CTX, EW1, EB1, EB2, GW, GB, LNG, LNB,
                     NW1, NB1, NW2, NB2, HW1, HB1, HW2, HB2, W2T, OUTP);
}

// Round 2
// 2388.966 us; speedup vs baseline: 1.8409x; 1.8409x over previous
//
#include <hip/hip_runtime.h>
#include <hip/hip_bf16.h>

#define TPB 256

typedef __attribute__((ext_vector_type(8))) short short8;
typedef __attribute__((ext_vector_type(4))) float f32x4;

__device__ __forceinline__ float fsigmoid(float x) {
  return __builtin_amdgcn_rcpf(1.0f + __expf(-x));
}
__device__ __forceinline__ float fsilu(float x) { return x * fsigmoid(x); }
__device__ __forceinline__ short bf16b(float x) {
  union { float f; unsigned u; } c; c.f = x;
  unsigned r = c.u + 0x7FFFu + ((c.u >> 16) & 1u);
  return (short)(r >> 16);
}

// ---- setup: build bf16 B-fragments for all 4 GEMMs into d_ws ----
// layout (bf16 elements):
//   EW1F @ 0     : [l][nt0..7][lane][e]  K=32(22 used), N=128 (pi|pj)
//   EW2F @ 8192  : [l][ks0..1][nt0..3][lane][e]  K=64, N=64
//   NW1F @ 16384 : [l][ks0..2][nt0..3][lane][e]  K=96(86 used), N=64
//   NW2F @ 28672 : [l][ks0..1][nt0..1][lane][e]  K=64, N=32(22 used)
// fragment value = W[k = 32*ks + 8*(lane>>4) + e][n = 16*nt + (lane&15)], zero-padded
__global__ void setup_kernel(const float* __restrict__ eW1, const float* __restrict__ eW2,
                             const float* __restrict__ nW1, const float* __restrict__ nW2,
                             unsigned short* __restrict__ WS) {
  int t = blockIdx.x * 256 + threadIdx.x;
  float val = 0.f;
  if (t < 8192) {                       // EW1F
    int l = t >> 12, r = t & 4095;
    int nt = r >> 9, lane = (r >> 3) & 63, e = r & 7;
    int k = 8 * (lane >> 4) + e, n = 16 * nt + (lane & 15);
    if (k < 22) val = (n < 64) ? eW1[l * 2816 + k * 64 + n]
                               : eW1[l * 2816 + (22 + k) * 64 + (n - 64)];
  } else if (t < 16384) {               // EW2F
    int u = t - 8192;
    int l = u >> 12, r = u & 4095;
    int ks = r >> 11, nt = (r >> 9) & 3, lane = (r >> 3) & 63, e = r & 7;
    int k = 32 * ks + 8 * (lane >> 4) + e, n = 16 * nt + (lane & 15);
    val = eW2[l * 4096 + k * 64 + n];
  } else if (t < 28672) {               // NW1F
    int u = t - 16384;
    int l = u / 6144, r = u % 6144;
    int ks = r >> 11, nt = (r >> 9) & 3, lane = (r >> 3) & 63, e = r & 7;
    int k = 32 * ks + 8 * (lane >> 4) + e, n = 16 * nt + (lane & 15);
    if (k < 86) val = nW1[l * 5504 + k * 64 + n];
  } else {                              // NW2F
    int u = t - 28672;
    int l = u >> 11, r = u & 2047;
    int ks = r >> 10, nt = (r >> 9) & 1, lane = (r >> 3) & 63, e = r & 7;
    int k = 32 * ks + 8 * (lane >> 4) + e, n = 16 * nt + (lane & 15);
    if (n < 22) val = nW2[l * 1408 + k * 22 + n];
  }
  WS[t] = (unsigned short)bf16b(val);
}

__launch_bounds__(TPB, 4)
__global__ void gnn_kernel(
    const float* __restrict__ X, const float* __restrict__ CTX,
    const float* __restrict__ EB1, const float* __restrict__ EB2,
    const float* __restrict__ GW, const float* __restrict__ GB,
    const float* __restrict__ LNG, const float* __restrict__ LNB,
    const float* __restrict__ NB1, const float* __restrict__ NB2,
    const float* __restrict__ HW1, const float* __restrict__ HB1,
    const float* __restrict__ HW2, const float* __restrict__ HB2,
    const unsigned short* __restrict__ WS, float* __restrict__ OUTP)
{
  __shared__ float sz[29 * 36];     // z (cols 22..35 zero)
  __shared__ float sin_[29 * 100];  // [zn(0:22) | macc(22:86) | zero pad]
  __shared__ float spp[29 * 132];   // [pi(0:64) | pj(64:128)]
  __shared__ float sh1[29 * 68];    // node-MLP hidden
  __shared__ float szm[24], shh[64], sob[24];

  const int b = blockIdx.x;
  const int tid = threadIdx.x;
  const int lane = tid & 63;
  const int w = tid >> 6;
  const int lr = lane & 15;   // fragment row/col index
  const int lg = lane >> 4;   // lane group 0..3
  const int kb = lg * 8;      // k base within a 32-wide k-step

  // ---- z = concat(x, context), zero-pad cols 22..35
  for (int t = tid; t < 29 * 36; t += TPB) {
    int i = t / 36, c = t - i * 36;
    float v = 0.f;
    if (c < 6) v = X[b * 174 + i * 6 + c];
    else if (c < 22) v = CTX[b * 464 + i * 16 + (c - 6)];
    sz[t] = v;
  }
  __syncthreads();

  #pragma unroll 1
  for (int l = 0; l < 2; ++l) {
    // ---- zero sin_ (macc region + pads)
    for (int t = tid; t < 29 * 100; t += TPB) sin_[t] = 0.f;
    __syncthreads();

    // ---- phase A: spp = bf16(z) @ EW1F (+eb1 on pi half)
    {
      int rt = w >> 1;
      int rowc = min(16 * rt + lr, 28);
      float4 z0 = *(const float4*)&sz[rowc * 36 + kb];
      float4 z1 = *(const float4*)&sz[rowc * 36 + kb + 4];
      short8 af;
      af[0] = bf16b(z0.x); af[1] = bf16b(z0.y); af[2] = bf16b(z0.z); af[3] = bf16b(z0.w);
      af[4] = bf16b(z1.x); af[5] = bf16b(z1.y); af[6] = bf16b(z1.z); af[7] = bf16b(z1.w);
      int ntb = 4 * (w & 1);
      const unsigned short* wp = WS + (l * 4096 + ntb * 512 + lane * 8);
      f32x4 acc[4];
      #pragma unroll
      for (int t = 0; t < 4; ++t) {
        short8 bfr = *(const short8*)(wp + t * 512);
        f32x4 zz = {0.f, 0.f, 0.f, 0.f};
        acc[t] = __builtin_amdgcn_mfma_f32_16x16x32_bf16(af, bfr, zz, 0, 0, 0);
      }
      #pragma unroll
      for (int t = 0; t < 4; ++t) {
        int n = 16 * (ntb + t) + lr;
        float bias = (ntb + t < 4) ? EB1[l * 64 + n] : 0.f;
        #pragma unroll
        for (int r = 0; r < 4; ++r) {
          int orow = 16 * rt + 4 * lg + r;
          if (orow < 29) spp[orow * 132 + n] = acc[t][r] + bias;
        }
      }
    }
    // ---- layernorm(z) -> sin_[:, 0:22] (same barrier region; disjoint LDS)
    {
      int d = lane;
      float lgam = 0.f, lbet = 0.f;
      if (d < 22) { lgam = LNG[l * 22 + d]; lbet = LNB[l * 22 + d]; }
      for (int i = w; i < 29; i += 4) {
        float v = (d < 22) ? sz[i * 36 + d] : 0.f;
        float s = v;
        #pragma unroll
        for (int m = 1; m < 64; m <<= 1) s += __shfl_xor(s, m, 64);
        float mu = s * (1.f / 22.f);
        float dz = (d < 22) ? (v - mu) : 0.f;
        float q = dz * dz;
        #pragma unroll
        for (int m = 1; m < 64; m <<= 1) q += __shfl_xor(q, m, 64);
        float rr = rsqrtf(q * (1.f / 22.f) + 1e-5f);
        if (d < 22) sin_[i * 100 + d] = dz * rr * lgam + lbet;
      }
    }
    __syncthreads();

    // ---- edge phase: m1=silu(pi+pj); m2=silu(m1@eW2+eb2); g=sigmoid(m2.gw+gb);
    //      sin_[i, 22+c] += m2*g   (53 tiles of 16 edges)
    {
      const unsigned short* wp = WS + (8192 + l * 4096 + lane * 8);
      short8 w2f[2][4];
      #pragma unroll
      for (int s = 0; s < 2; ++s)
        #pragma unroll
        for (int t = 0; t < 4; ++t)
          w2f[s][t] = *(const short8*)(wp + s * 2048 + t * 512);
      float eb2c[4], gwc[4];
      #pragma unroll
      for (int t = 0; t < 4; ++t) {
        eb2c[t] = EB2[l * 64 + 16 * t + lr];
        gwc[t]  = GW [l * 64 + 16 * t + lr];
      }
      float gbv = GB[l];

      for (int t = w; t < 53; t += 4) {
        int ec = min(t * 16 + lr, 840);
        int ia = (int)((unsigned)ec / 29u);
        int ja = ec - ia * 29;
        const float* pbase = &spp[ia * 132 + kb];
        const float* qbase = &spp[ja * 132 + 64 + kb];
        short8 af[2];
        #pragma unroll
        for (int s = 0; s < 2; ++s) {
          float4 p0 = *(const float4*)(pbase + 32 * s);
          float4 p1 = *(const float4*)(pbase + 32 * s + 4);
          float4 q0 = *(const float4*)(qbase + 32 * s);
          float4 q1 = *(const float4*)(qbase + 32 * s + 4);
          af[s][0] = bf16b(fsilu(p0.x + q0.x));
          af[s][1] = bf16b(fsilu(p0.y + q0.y));
          af[s][2] = bf16b(fsilu(p0.z + q0.z));
          af[s][3] = bf16b(fsilu(p0.w + q0.w));
          af[s][4] = bf16b(fsilu(p1.x + q1.x));
          af[s][5] = bf16b(fsilu(p1.y + q1.y));
          af[s][6] = bf16b(fsilu(p1.z + q1.z));
          af[s][7] = bf16b(fsilu(p1.w + q1.w));
        }
        f32x4 acc0 = {0.f,0.f,0.f,0.f}, acc1 = {0.f,0.f,0.f,0.f};
        f32x4 acc2 = {0.f,0.f,0.f,0.f}, acc3 = {0.f,0.f,0.f,0.f};
        #pragma unroll
        for (int s = 0; s < 2; ++s) {
          acc0 = __builtin_amdgcn_mfma_f32_16x16x32_bf16(af[s], w2f[s][0], acc0, 0, 0, 0);
          acc1 = __builtin_amdgcn_mfma_f32_16x16x32_bf16(af[s], w2f[s][1], acc1, 0, 0, 0);
          acc2 = __builtin_amdgcn_mfma_f32_16x16x32_bf16(af[s], w2f[s][2], acc2, 0, 0, 0);
          acc3 = __builtin_amdgcn_mfma_f32_16x16x32_bf16(af[s], w2f[s][3], acc3, 0, 0, 0);
        }
        float m2v[4][4];
        float gp0 = 0.f, gp1 = 0.f, gp2 = 0.f, gp3 = 0.f;
        #pragma unroll
        for (int r = 0; r < 4; ++r) {
          m2v[0][r] = fsilu(acc0[r] + eb2c[0]);
          m2v[1][r] = fsilu(acc1[r] + eb2c[1]);
          m2v[2][r] = fsilu(acc2[r] + eb2c[2]);
          m2v[3][r] = fsilu(acc3[r] + eb2c[3]);
        }
        gp0 = m2v[0][0]*gwc[0] + m2v[1][0]*gwc[1] + m2v[2][0]*gwc[2] + m2v[3][0]*gwc[3];
        gp1 = m2v[0][1]*gwc[0] + m2v[1][1]*gwc[1] + m2v[2][1]*gwc[2] + m2v[3][1]*gwc[3];
        gp2 = m2v[0][2]*gwc[0] + m2v[1][2]*gwc[1] + m2v[2][2]*gwc[2] + m2v[3][2]*gwc[3];
        gp3 = m2v[0][3]*gwc[0] + m2v[1][3]*gwc[1] + m2v[2][3]*gwc[2] + m2v[3][3]*gwc[3];
        float gv[4];
        {
          float g0 = gp0, g1 = gp1, g2 = gp2, g3 = gp3;
          #pragma unroll
          for (int m = 1; m < 16; m <<= 1) {
            g0 += __shfl_xor(g0, m, 64);
            g1 += __shfl_xor(g1, m, 64);
            g2 += __shfl_xor(g2, m, 64);
            g3 += __shfl_xor(g3, m, 64);
          }
          float gg[4] = {g0, g1, g2, g3};
          #pragma unroll
          for (int r = 0; r < 4; ++r) {
            int er = t * 16 + 4 * lg + r;
            gv[r] = (er < 841) ? fsigmoid(gg[r] + gbv) : 0.f;
          }
        }
        #pragma unroll
        for (int r = 0; r < 4; ++r) {
          int er = min(t * 16 + 4 * lg + r, 840);
          int ir = (int)((unsigned)er / 29u);
          float* dst = &sin_[ir * 100 + 22 + lr];
          unsafeAtomicAdd(dst +  0, m2v[0][r] * gv[r]);
          unsafeAtomicAdd(dst + 16, m2v[1][r] * gv[r]);
          unsafeAtomicAdd(dst + 32, m2v[2][r] * gv[r]);
          unsafeAtomicAdd(dst + 48, m2v[3][r] * gv[r]);
        }
      }
    }
    __syncthreads();

    // ---- phase C: h1 = silu(bf16([zn|macc]) @ NW1F + nb1) -> sh1
    {
      int rt = w >> 1;
      int ntb = 2 * (w & 1);
      int rowc = min(16 * rt + lr, 28);
      const unsigned short* wp = WS + (16384 + l * 6144 + ntb * 512 + lane * 8);
      f32x4 acc[2] = {{0.f,0.f,0.f,0.f}, {0.f,0.f,0.f,0.f}};
      #pragma unroll
      for (int s = 0; s < 3; ++s) {
        const float* ab = &sin_[rowc * 100 + kb + 32 * s];
        float4 a0 = *(const float4*)ab;
        float4 a1 = *(const float4*)(ab + 4);
        short8 af;
        af[0] = bf16b(a0.x); af[1] = bf16b(a0.y); af[2] = bf16b(a0.z); af[3] = bf16b(a0.w);
        af[4] = bf16b(a1.x); af[5] = bf16b(a1.y); af[6] = bf16b(a1.z); af[7] = bf16b(a1.w);
        #pragma unroll
        for (int t = 0; t < 2; ++t) {
          short8 bfr = *(const short8*)(wp + s * 2048 + t * 512);
          acc[t] = __builtin_amdgcn_mfma_f32_16x16x32_bf16(af, bfr, acc[t], 0, 0, 0);
        }
      }
      #pragma unroll
      for (int t = 0; t < 2; ++t) {
        int n = 16 * (ntb + t) + lr;
        float bias = NB1[l * 64 + n];
        #pragma unroll
        for (int r = 0; r < 4; ++r) {
          int orow = 16 * rt + 4 * lg + r;
          if (orow < 29) sh1[orow * 68 + n] = fsilu(acc[t][r] + bias);
        }
      }
    }
    __syncthreads();

    // ---- phase D: z += bf16(h1) @ NW2F + nb2
    {
      int rt = w & 1;
      int nt = w >> 1;
      int rowc = min(16 * rt + lr, 28);
      int d = 16 * nt + lr;
      const unsigned short* wp = WS + (28672 + l * 2048 + nt * 512 + lane * 8);
      f32x4 acc = {0.f, 0.f, 0.f, 0.f};
      #pragma unroll
      for (int s = 0; s < 2; ++s) {
        const float* ab = &sh1[rowc * 68 + kb + 32 * s];
        float4 a0 = *(const float4*)ab;
        float4 a1 = *(const float4*)(ab + 4);
        short8 af;
        af[0] = bf16b(a0.x); af[1] = bf16b(a0.y); af[2] = bf16b(a0.z); af[3] = bf16b(a0.w);
        af[4] = bf16b(a1.x); af[5] = bf16b(a1.y); af[6] = bf16b(a1.z); af[7] = bf16b(a1.w);
        short8 bfr = *(const short8*)(wp + s * 1024);
        acc = __builtin_amdgcn_mfma_f32_16x16x32_bf16(af, bfr, acc, 0, 0, 0);
      }
      float bias = (d < 22) ? NB2[l * 22 + d] : 0.f;
      #pragma unroll
      for (int r = 0; r < 4; ++r) {
        int orow = 16 * rt + 4 * lg + r;
        if (orow < 29 && d < 22) sz[orow * 36 + d] += acc[r] + bias;
      }
    }
    __syncthreads();
  }

  // ---- head: mean pool, relu MLP, padded write
  if (tid < 22) {
    float s = 0.f;
    #pragma unroll
    for (int i = 0; i < 29; ++i) s += sz[i * 36 + tid];
    szm[tid] = s * (1.f / 29.f);
  }
  __syncthreads();
  if (tid < 64) {
    float a = HB1[tid];
    #pragma unroll
    for (int d = 0; d < 22; ++d) a += szm[d] * HW1[d * 64 + tid];
    shh[tid] = fmaxf(a, 0.f);
  }
  __syncthreads();
  if (tid < 24) {
    float a = HB2[tid];
    #pragma unroll
    for (int m = 0; m < 64; ++m) a += shh[m] * HW2[m * 24 + tid];
    sob[tid] = a;
  }
  __syncthreads();
  for (int t = tid; t < 29 * 12; t += TPB) {
    OUTP[b * 348 + t] = (t < 24) ? sob[t] : 0.f;
  }
}

extern "C" void kernel_launch(void* const* d_in, const int* in_sizes, int n_in,
                              void* d_out, int out_size, void* d_ws, size_t ws_size,
                              hipStream_t stream) {
  const float* X   = (const float*)d_in[0];
  const float* CTX = (const float*)d_in[1];
  const float* EW1 = (const float*)d_in[2];
  const float* EB1 = (const float*)d_in[3];
  const float* EW2 = (const float*)d_in[4];
  const float* EB2 = (const float*)d_in[5];
  const float* GW  = (const float*)d_in[6];
  const float* GB  = (const float*)d_in[7];
  const float* LNG = (const float*)d_in[8];
  const float* LNB = (const float*)d_in[9];
  const float* NW1 = (const float*)d_in[10];
  const float* NB1 = (const float*)d_in[11];
  const float* NW2 = (const float*)d_in[12];
  const float* NB2 = (const float*)d_in[13];
  const float* HW1 = (const float*)d_in[14];
  const float* HB1 = (const float*)d_in[15];
  const float* HW2 = (const float*)d_in[16];
  const float* HB2 = (const float*)d_in[17];
  float* OUTP = (float*)d_out;
  unsigned short* WS = (unsigned short*)d_ws;  // 32768 bf16 = 64 KB

  hipLaunchKernelGGL(setup_kernel, dim3(128), dim3(256), 0, stream,
                     EW1, EW2, NW1, NW2, WS);
  hipLaunchKernelGGL(gnn_kernel, dim3(4096), dim3(TPB), 0, stream,
                     X, CTX, EB1, EB2, GW, GB, LNG, LNB, NB1, NB2,
                     HW1, HB1, HW2, HB2, WS, OUTP);
}

// Round 3
// 2388.058 us; speedup vs baseline: 1.8416x; 1.0004x over previous
//
#include <hip/hip_runtime.h>
#include <hip/hip_bf16.h>

#define TPB 256

typedef __attribute__((ext_vector_type(8))) short short8;
typedef __attribute__((ext_vector_type(4))) float f32x4;

__device__ __forceinline__ float fsigmoid(float x) {
  return __builtin_amdgcn_rcpf(1.0f + __expf(-x));
}
__device__ __forceinline__ float fsilu(float x) { return x * fsigmoid(x); }
__device__ __forceinline__ short bf16b(float x) {
  union { float f; unsigned u; } c; c.f = x;
  unsigned r = c.u + 0x7FFFu + ((c.u >> 16) & 1u);
  return (short)(r >> 16);
}
// packed f32x2 -> bf16x2 (v_cvt_pk_bf16_f32)
__device__ __forceinline__ short8 pack8(const float* v) {
  short8 r;
  #pragma unroll
  for (int m = 0; m < 4; ++m) {
    __hip_bfloat162 h = __float22bfloat162_rn(make_float2(v[2 * m], v[2 * m + 1]));
    short2 s2 = *reinterpret_cast<const short2*>(&h);
    r[2 * m] = s2.x; r[2 * m + 1] = s2.y;
  }
  return r;
}

// ---- setup: build bf16 B-fragments for all 4 GEMMs into d_ws ----
//   EW1F @ 0     : [l][nt0..7][lane][e]  K=32(22 used), N=128 (pi|pj)
//   EW2F @ 8192  : [l][ks0..1][nt0..3][lane][e]  K=64, N=64
//   NW1F @ 16384 : [l][ks0..2][nt0..3][lane][e]  K=96(86 used), N=64
//   NW2F @ 28672 : [l][ks0..1][nt0..1][lane][e]  K=64, N=32(22 used)
// fragment value = W[k = 32*ks + 8*(lane>>4) + e][n = 16*nt + (lane&15)], zero-padded
__global__ void setup_kernel(const float* __restrict__ eW1, const float* __restrict__ eW2,
                             const float* __restrict__ nW1, const float* __restrict__ nW2,
                             unsigned short* __restrict__ WS) {
  int t = blockIdx.x * 256 + threadIdx.x;
  float val = 0.f;
  if (t < 8192) {                       // EW1F
    int l = t >> 12, r = t & 4095;
    int nt = r >> 9, lane = (r >> 3) & 63, e = r & 7;
    int k = 8 * (lane >> 4) + e, n = 16 * nt + (lane & 15);
    if (k < 22) val = (n < 64) ? eW1[l * 2816 + k * 64 + n]
                               : eW1[l * 2816 + (22 + k) * 64 + (n - 64)];
  } else if (t < 16384) {               // EW2F
    int u = t - 8192;
    int l = u >> 12, r = u & 4095;
    int ks = r >> 11, nt = (r >> 9) & 3, lane = (r >> 3) & 63, e = r & 7;
    int k = 32 * ks + 8 * (lane >> 4) + e, n = 16 * nt + (lane & 15);
    val = eW2[l * 4096 + k * 64 + n];
  } else if (t < 28672) {               // NW1F
    int u = t - 16384;
    int l = u / 6144, r = u % 6144;
    int ks = r >> 11, nt = (r >> 9) & 3, lane = (r >> 3) & 63, e = r & 7;
    int k = 32 * ks + 8 * (lane >> 4) + e, n = 16 * nt + (lane & 15);
    if (k < 86) val = nW1[l * 5504 + k * 64 + n];
  } else {                              // NW2F
    int u = t - 28672;
    int l = u >> 11, r = u & 2047;
    int ks = r >> 10, nt = (r >> 9) & 1, lane = (r >> 3) & 63, e = r & 7;
    int k = 32 * ks + 8 * (lane >> 4) + e, n = 16 * nt + (lane & 15);
    if (n < 22) val = nW2[l * 1408 + k * 22 + n];
  }
  WS[t] = (unsigned short)bf16b(val);
}

// (256,3): VGPR budget ~168 so the 8 short8 edge-weight fragments (32 VGPR)
// stay loop-resident. At (256,4)/128 the allocator rematerialized them as
// global loads inside the edge loop -> VGPR_Count=56, latency-bound (R2).
__launch_bounds__(TPB, 3)
__global__ void gnn_kernel(
    const float* __restrict__ X, const float* __restrict__ CTX,
    const float* __restrict__ EB1, const float* __restrict__ EB2,
    const float* __restrict__ GW, const float* __restrict__ GB,
    const float* __restrict__ LNG, const float* __restrict__ LNB,
    const float* __restrict__ NB1, const float* __restrict__ NB2,
    const float* __restrict__ HW1, const float* __restrict__ HB1,
    const float* __restrict__ HW2, const float* __restrict__ HB2,
    const unsigned short* __restrict__ WS, float* __restrict__ OUTP)
{
  __shared__ float sz[29 * 36];     // z (cols 22..35 zero)
  __shared__ float sin_[29 * 100];  // [zn(0:22) | macc(22:86) | zero pad]
  __shared__ float spp[29 * 132];   // [pi(0:64) | pj(64:128)]
  __shared__ float sh1[29 * 68];    // node-MLP hidden
  __shared__ float szm[24], shh[64], sob[24];

  const int b = blockIdx.x;
  const int tid = threadIdx.x;
  const int lane = tid & 63;
  const int w = tid >> 6;
  const int lr = lane & 15;   // fragment row/col index
  const int lg = lane >> 4;   // lane group 0..3
  const int kb = lg * 8;      // k base within a 32-wide k-step

  // ---- z = concat(x, context), zero-pad cols 22..35
  for (int t = tid; t < 29 * 36; t += TPB) {
    int i = t / 36, c = t - i * 36;
    float v = 0.f;
    if (c < 6) v = X[b * 174 + i * 6 + c];
    else if (c < 22) v = CTX[b * 464 + i * 16 + (c - 6)];
    sz[t] = v;
  }
  __syncthreads();

  #pragma unroll 1
  for (int l = 0; l < 2; ++l) {
    // ---- zero sin_ (macc region + pads)
    for (int t = tid; t < 29 * 100; t += TPB) sin_[t] = 0.f;
    __syncthreads();

    // ---- phase A: spp = bf16(z) @ EW1F (+eb1 on pi half)
    {
      int rt = w >> 1;
      int rowc = min(16 * rt + lr, 28);
      float zr[8];
      *(float4*)&zr[0] = *(const float4*)&sz[rowc * 36 + kb];
      *(float4*)&zr[4] = *(const float4*)&sz[rowc * 36 + kb + 4];
      short8 af = pack8(zr);
      int ntb = 4 * (w & 1);
      const unsigned short* wp = WS + (l * 4096 + ntb * 512 + lane * 8);
      f32x4 acc[4];
      #pragma unroll
      for (int t = 0; t < 4; ++t) {
        short8 bfr = *(const short8*)(wp + t * 512);
        f32x4 zz = {0.f, 0.f, 0.f, 0.f};
        acc[t] = __builtin_amdgcn_mfma_f32_16x16x32_bf16(af, bfr, zz, 0, 0, 0);
      }
      #pragma unroll
      for (int t = 0; t < 4; ++t) {
        int n = 16 * (ntb + t) + lr;
        float bias = (ntb + t < 4) ? EB1[l * 64 + n] : 0.f;
        #pragma unroll
        for (int r = 0; r < 4; ++r) {
          int orow = 16 * rt + 4 * lg + r;
          if (orow < 29) spp[orow * 132 + n] = acc[t][r] + bias;
        }
      }
    }
    // ---- layernorm(z) -> sin_[:, 0:22] (same barrier region; disjoint LDS)
    {
      int d = lane;
      float lgam = 0.f, lbet = 0.f;
      if (d < 22) { lgam = LNG[l * 22 + d]; lbet = LNB[l * 22 + d]; }
      for (int i = w; i < 29; i += 4) {
        float v = (d < 22) ? sz[i * 36 + d] : 0.f;
        float s = v;
        #pragma unroll
        for (int m = 1; m < 64; m <<= 1) s += __shfl_xor(s, m, 64);
        float mu = s * (1.f / 22.f);
        float dz = (d < 22) ? (v - mu) : 0.f;
        float q = dz * dz;
        #pragma unroll
        for (int m = 1; m < 64; m <<= 1) q += __shfl_xor(q, m, 64);
        float rr = rsqrtf(q * (1.f / 22.f) + 1e-5f);
        if (d < 22) sin_[i * 100 + d] = dz * rr * lgam + lbet;
      }
    }
    __syncthreads();

    // ---- edge phase: m1=silu(pi+pj); m2=silu(m1@eW2+eb2); g=sigmoid(m2.gw+gb);
    //      sin_[i, 22+c] += m2*g   (53 tiles of 16 edges)
    {
      const unsigned short* wp = WS + (8192 + l * 4096 + lane * 8);
      short8 w2f[2][4];
      #pragma unroll
      for (int s = 0; s < 2; ++s)
        #pragma unroll
        for (int t = 0; t < 4; ++t) {
          w2f[s][t] = *(const short8*)(wp + s * 2048 + t * 512);
          asm volatile("" : "+v"(w2f[s][t]));   // pin: no remat inside loop
        }
      float eb2c[4], gwc[4];
      #pragma unroll
      for (int t = 0; t < 4; ++t) {
        eb2c[t] = EB2[l * 64 + 16 * t + lr];
        gwc[t]  = GW [l * 64 + 16 * t + lr];
      }
      float gbv = GB[l];

      for (int t = w; t < 53; t += 4) {
        int ec = min(t * 16 + lr, 840);
        int ia = (int)((unsigned)ec / 29u);
        int ja = ec - ia * 29;
        const float* pbase = &spp[ia * 132 + kb];
        const float* qbase = &spp[ja * 132 + 64 + kb];
        short8 af[2];
        #pragma unroll
        for (int s = 0; s < 2; ++s) {
          float4 p0 = *(const float4*)(pbase + 32 * s);
          float4 p1 = *(const float4*)(pbase + 32 * s + 4);
          float4 q0 = *(const float4*)(qbase + 32 * s);
          float4 q1 = *(const float4*)(qbase + 32 * s + 4);
          float m1[8];
          m1[0] = fsilu(p0.x + q0.x);
          m1[1] = fsilu(p0.y + q0.y);
          m1[2] = fsilu(p0.z + q0.z);
          m1[3] = fsilu(p0.w + q0.w);
          m1[4] = fsilu(p1.x + q1.x);
          m1[5] = fsilu(p1.y + q1.y);
          m1[6] = fsilu(p1.z + q1.z);
          m1[7] = fsilu(p1.w + q1.w);
          af[s] = pack8(m1);
        }
        f32x4 acc0 = {0.f,0.f,0.f,0.f}, acc1 = {0.f,0.f,0.f,0.f};
        f32x4 acc2 = {0.f,0.f,0.f,0.f}, acc3 = {0.f,0.f,0.f,0.f};
        #pragma unroll
        for (int s = 0; s < 2; ++s) {
          acc0 = __builtin_amdgcn_mfma_f32_16x16x32_bf16(af[s], w2f[s][0], acc0, 0, 0, 0);
          acc1 = __builtin_amdgcn_mfma_f32_16x16x32_bf16(af[s], w2f[s][1], acc1, 0, 0, 0);
          acc2 = __builtin_amdgcn_mfma_f32_16x16x32_bf16(af[s], w2f[s][2], acc2, 0, 0, 0);
          acc3 = __builtin_amdgcn_mfma_f32_16x16x32_bf16(af[s], w2f[s][3], acc3, 0, 0, 0);
        }
        float m2v[4][4];
        #pragma unroll
        for (int r = 0; r < 4; ++r) {
          m2v[0][r] = fsilu(acc0[r] + eb2c[0]);
          m2v[1][r] = fsilu(acc1[r] + eb2c[1]);
          m2v[2][r] = fsilu(acc2[r] + eb2c[2]);
          m2v[3][r] = fsilu(acc3[r] + eb2c[3]);
        }
        float g0 = m2v[0][0]*gwc[0] + m2v[1][0]*gwc[1] + m2v[2][0]*gwc[2] + m2v[3][0]*gwc[3];
        float g1 = m2v[0][1]*gwc[0] + m2v[1][1]*gwc[1] + m2v[2][1]*gwc[2] + m2v[3][1]*gwc[3];
        float g2 = m2v[0][2]*gwc[0] + m2v[1][2]*gwc[1] + m2v[2][2]*gwc[2] + m2v[3][2]*gwc[3];
        float g3 = m2v[0][3]*gwc[0] + m2v[1][3]*gwc[1] + m2v[2][3]*gwc[2] + m2v[3][3]*gwc[3];
        #pragma unroll
        for (int m = 1; m < 16; m <<= 1) {
          g0 += __shfl_xor(g0, m, 64);
          g1 += __shfl_xor(g1, m, 64);
          g2 += __shfl_xor(g2, m, 64);
          g3 += __shfl_xor(g3, m, 64);
        }
        float gv[4];
        {
          float gg[4] = {g0, g1, g2, g3};
          #pragma unroll
          for (int r = 0; r < 4; ++r) {
            int er = t * 16 + 4 * lg + r;
            gv[r] = (er < 841) ? fsigmoid(gg[r] + gbv) : 0.f;
          }
        }
        #pragma unroll
        for (int r = 0; r < 4; ++r) {
          int er = min(t * 16 + 4 * lg + r, 840);
          int ir = (int)((unsigned)er / 29u);
          float* dst = &sin_[ir * 100 + 22 + lr];
          unsafeAtomicAdd(dst +  0, m2v[0][r] * gv[r]);
          unsafeAtomicAdd(dst + 16, m2v[1][r] * gv[r]);
          unsafeAtomicAdd(dst + 32, m2v[2][r] * gv[r]);
          unsafeAtomicAdd(dst + 48, m2v[3][r] * gv[r]);
        }
      }
    }
    __syncthreads();

    // ---- phase C: h1 = silu(bf16([zn|macc]) @ NW1F + nb1) -> sh1
    {
      int rt = w >> 1;
      int ntb = 2 * (w & 1);
      int rowc = min(16 * rt + lr, 28);
      const unsigned short* wp = WS + (16384 + l * 6144 + ntb * 512 + lane * 8);
      f32x4 acc[2] = {{0.f,0.f,0.f,0.f}, {0.f,0.f,0.f,0.f}};
      #pragma unroll
      for (int s = 0; s < 3; ++s) {
        float ar[8];
        *(float4*)&ar[0] = *(const float4*)&sin_[rowc * 100 + kb + 32 * s];
        *(float4*)&ar[4] = *(const float4*)&sin_[rowc * 100 + kb + 32 * s + 4];
        short8 af = pack8(ar);
        #pragma unroll
        for (int t = 0; t < 2; ++t) {
          short8 bfr = *(const short8*)(wp + s * 2048 + t * 512);
          acc[t] = __builtin_amdgcn_mfma_f32_16x16x32_bf16(af, bfr, acc[t], 0, 0, 0);
        }
      }
      #pragma unroll
      for (int t = 0; t < 2; ++t) {
        int n = 16 * (ntb + t) + lr;
        float bias = NB1[l * 64 + n];
        #pragma unroll
        for (int r = 0; r < 4; ++r) {
          int orow = 16 * rt + 4 * lg + r;
          if (orow < 29) sh1[orow * 68 + n] = fsilu(acc[t][r] + bias);
        }
      }
    }
    __syncthreads();

    // ---- phase D: z += bf16(h1) @ NW2F + nb2
    {
      int rt = w & 1;
      int nt = w >> 1;
      int rowc = min(16 * rt + lr, 28);
      int d = 16 * nt + lr;
      const unsigned short* wp = WS + (28672 + l * 2048 + nt * 512 + lane * 8);
      f32x4 acc = {0.f, 0.f, 0.f, 0.f};
      #pragma unroll
      for (int s = 0; s < 2; ++s) {
        float ar[8];
        *(float4*)&ar[0] = *(const float4*)&sh1[rowc * 68 + kb + 32 * s];
        *(float4*)&ar[4] = *(const float4*)&sh1[rowc * 68 + kb + 32 * s + 4];
        short8 af = pack8(ar);
        short8 bfr = *(const short8*)(wp + s * 1024);
        acc = __builtin_amdgcn_mfma_f32_16x16x32_bf16(af, bfr, acc, 0, 0, 0);
      }
      float bias = (d < 22) ? NB2[l * 22 + d] : 0.f;
      #pragma unroll
      for (int r = 0; r < 4; ++r) {
        int orow = 16 * rt + 4 * lg + r;
        if (orow < 29 && d < 22) sz[orow * 36 + d] += acc[r] + bias;
      }
    }
    __syncthreads();
  }

  // ---- head: mean pool, relu MLP, padded write
  if (tid < 22) {
    float s = 0.f;
    #pragma unroll
    for (int i = 0; i < 29; ++i) s += sz[i * 36 + tid];
    szm[tid] = s * (1.f / 29.f);
  }
  __syncthreads();
  if (tid < 64) {
    float a = HB1[tid];
    #pragma unroll
    for (int d = 0; d < 22; ++d) a += szm[d] * HW1[d * 64 + tid];
    shh[tid] = fmaxf(a, 0.f);
  }
  __syncthreads();
  if (tid < 24) {
    float a = HB2[tid];
    #pragma unroll
    for (int m = 0; m < 64; ++m) a += shh[m] * HW2[m * 24 + tid];
    sob[tid] = a;
  }
  __syncthreads();
  for (int t = tid; t < 29 * 12; t += TPB) {
    OUTP[b * 348 + t] = (t < 24) ? sob[t] : 0.f;
  }
}

extern "C" void kernel_launch(void* const* d_in, const int* in_sizes, int n_in,
                              void* d_out, int out_size, void* d_ws, size_t ws_size,
                              hipStream_t stream) {
  const float* X   = (const float*)d_in[0];
  const float* CTX = (const float*)d_in[1];
  const float* EW1 = (const float*)d_in[2];
  const float* EB1 = (const float*)d_in[3];
  const float* EW2 = (const float*)d_in[4];
  const float* EB2 = (const float*)d_in[5];
  const float* GW  = (const float*)d_in[6];
  const float* GB  = (const float*)d_in[7];
  const float* LNG = (const float*)d_in[8];
  const float* LNB = (const float*)d_in[9];
  const float* NW1 = (const float*)d_in[10];
  const float* NB1 = (const float*)d_in[11];
  const float* NW2 = (const float*)d_in[12];
  const float* NB2 = (const float*)d_in[13];
  const float* HW1 = (const float*)d_in[14];
  const float* HB1 = (const float*)d_in[15];
  const float* HW2 = (const float*)d_in[16];
  const float* HB2 = (const float*)d_in[17];
  float* OUTP = (float*)d_out;
  unsigned short* WS = (unsigned short*)d_ws;  // 32768 bf16 = 64 KB

  hipLaunchKernelGGL(setup_kernel, dim3(128), dim3(256), 0, stream,
                     EW1, EW2, NW1, NW2, WS);
  hipLaunchKernelGGL(gnn_kernel, dim3(4096), dim3(TPB), 0, stream,
                     X, CTX, EB1, EB2, GW, GB, LNG, LNB, NB1, NB2,
                     HW1, HB1, HW2, HB2, WS, OUTP);
}

// Round 4
// 2345.310 us; speedup vs baseline: 1.8752x; 1.0182x over previous
//
#include <hip/hip_runtime.h>
#include <hip/hip_bf16.h>

#define TPB 256

typedef __attribute__((ext_vector_type(8))) short short8;
typedef __attribute__((ext_vector_type(4))) float f32x4;

__device__ __forceinline__ float fsigmoid(float x) {
  return __builtin_amdgcn_rcpf(1.0f + __expf(-x));
}
__device__ __forceinline__ float fsilu(float x) { return x * fsigmoid(x); }
__device__ __forceinline__ short bf16b(float x) {
  union { float f; unsigned u; } c; c.f = x;
  unsigned r = c.u + 0x7FFFu + ((c.u >> 16) & 1u);
  return (short)(r >> 16);
}
// packed f32x2 -> bf16x2 (v_cvt_pk_bf16_f32)
__device__ __forceinline__ short8 pack8(const float* v) {
  short8 r;
  #pragma unroll
  for (int m = 0; m < 4; ++m) {
    __hip_bfloat162 h = __float22bfloat162_rn(make_float2(v[2 * m], v[2 * m + 1]));
    short2 s2 = *reinterpret_cast<const short2*>(&h);
    r[2 * m] = s2.x; r[2 * m + 1] = s2.y;
  }
  return r;
}
// x += row_ror(x, N) within each 16-lane DPP row: rotation-reduce, pure VALU.
template<int CTRL>
__device__ __forceinline__ float dpp_add(float x) {
  int xi = __builtin_bit_cast(int, x);
  int yi = __builtin_amdgcn_update_dpp(0, xi, CTRL, 0xF, 0xF, true);
  return x + __builtin_bit_cast(float, yi);
}
__device__ __forceinline__ float row16_sum(float x) {
  x = dpp_add<0x121>(x);  // row_ror:1
  x = dpp_add<0x122>(x);  // row_ror:2
  x = dpp_add<0x124>(x);  // row_ror:4
  x = dpp_add<0x128>(x);  // row_ror:8
  return x;
}

// ---- setup: build bf16 B-fragments for all 4 GEMMs into d_ws ----
//   EW1F @ 0     : [l][nt0..7][lane][e]  K=32(22 used), N=128 (pi|pj)
//   EW2F @ 8192  : [l][ks0..1][nt0..3][lane][e]  K=64, N=64
//   NW1F @ 16384 : [l][ks0..2][nt0..3][lane][e]  K=96(86 used), N=64
//   NW2F @ 28672 : [l][ks0..1][nt0..1][lane][e]  K=64, N=32(22 used)
// fragment value = W[k = 32*ks + 8*(lane>>4) + e][n = 16*nt + (lane&15)], zero-padded
__global__ void setup_kernel(const float* __restrict__ eW1, const float* __restrict__ eW2,
                             const float* __restrict__ nW1, const float* __restrict__ nW2,
                             unsigned short* __restrict__ WS) {
  int t = blockIdx.x * 256 + threadIdx.x;
  float val = 0.f;
  if (t < 8192) {                       // EW1F
    int l = t >> 12, r = t & 4095;
    int nt = r >> 9, lane = (r >> 3) & 63, e = r & 7;
    int k = 8 * (lane >> 4) + e, n = 16 * nt + (lane & 15);
    if (k < 22) val = (n < 64) ? eW1[l * 2816 + k * 64 + n]
                               : eW1[l * 2816 + (22 + k) * 64 + (n - 64)];
  } else if (t < 16384) {               // EW2F
    int u = t - 8192;
    int l = u >> 12, r = u & 4095;
    int ks = r >> 11, nt = (r >> 9) & 3, lane = (r >> 3) & 63, e = r & 7;
    int k = 32 * ks + 8 * (lane >> 4) + e, n = 16 * nt + (lane & 15);
    val = eW2[l * 4096 + k * 64 + n];
  } else if (t < 28672) {               // NW1F
    int u = t - 16384;
    int l = u / 6144, r = u % 6144;
    int ks = r >> 11, nt = (r >> 9) & 3, lane = (r >> 3) & 63, e = r & 7;
    int k = 32 * ks + 8 * (lane >> 4) + e, n = 16 * nt + (lane & 15);
    if (k < 86) val = nW1[l * 5504 + k * 64 + n];
  } else {                              // NW2F
    int u = t - 28672;
    int l = u >> 11, r = u & 2047;
    int ks = r >> 10, nt = (r >> 9) & 1, lane = (r >> 3) & 63, e = r & 7;
    int k = 32 * ks + 8 * (lane >> 4) + e, n = 16 * nt + (lane & 15);
    if (n < 22) val = nW2[l * 1408 + k * 22 + n];
  }
  WS[t] = (unsigned short)bf16b(val);
}

__launch_bounds__(TPB, 3)
__global__ void gnn_kernel(
    const float* __restrict__ X, const float* __restrict__ CTX,
    const float* __restrict__ EB1, const float* __restrict__ EB2,
    const float* __restrict__ GW, const float* __restrict__ GB,
    const float* __restrict__ LNG, const float* __restrict__ LNB,
    const float* __restrict__ NB1, const float* __restrict__ NB2,
    const float* __restrict__ HW1, const float* __restrict__ HB1,
    const float* __restrict__ HW2, const float* __restrict__ HB2,
    const unsigned short* __restrict__ WS, float* __restrict__ OUTP)
{
  __shared__ float sz[29 * 36];          // z (cols 22..35 zero)
  __shared__ float sin_[29 * 100];       // [zn(0:22) | macc(22:86) | zero pad]
  __shared__ float spp[29 * 132];        // [pi(0:64) | pj(64:128)]
  __shared__ float sh1[29 * 68];         // node-MLP hidden
  __shared__ unsigned short sww[4096];   // edge-weight fragments, current layer (8 KB)
  __shared__ float szm[24], shh[64], sob[24];

  const int b = blockIdx.x;
  const int tid = threadIdx.x;
  const int lane = tid & 63;
  const int w = tid >> 6;
  const int lr = lane & 15;   // fragment row/col index
  const int lg = lane >> 4;   // lane group 0..3
  const int kb = lg * 8;      // k base within a 32-wide k-step

  // ---- z = concat(x, context), zero-pad cols 22..35
  for (int t = tid; t < 29 * 36; t += TPB) {
    int i = t / 36, c = t - i * 36;
    float v = 0.f;
    if (c < 6) v = X[b * 174 + i * 6 + c];
    else if (c < 22) v = CTX[b * 464 + i * 16 + (c - 6)];
    sz[t] = v;
  }
  __syncthreads();

  #pragma unroll 1
  for (int l = 0; l < 2; ++l) {
    // ---- region 0: zero sin_ (vectorized) + stage edge weights into LDS
    {
      float4 z4 = {0.f, 0.f, 0.f, 0.f};
      for (int t = tid; t < 725; t += TPB) ((float4*)sin_)[t] = z4;
      const short8* src = (const short8*)(WS + 8192 + l * 4096);
      ((short8*)sww)[tid]       = src[tid];
      ((short8*)sww)[tid + 256] = src[tid + 256];
    }
    __syncthreads();

    // ---- region 1: phase A (spp = bf16(z) @ EW1F + eb1) and serial LN
    {
      int rt = w >> 1;
      int rowc = min(16 * rt + lr, 28);
      float zr[8];
      *(float4*)&zr[0] = *(const float4*)&sz[rowc * 36 + kb];
      *(float4*)&zr[4] = *(const float4*)&sz[rowc * 36 + kb + 4];
      short8 af = pack8(zr);
      int ntb = 4 * (w & 1);
      const unsigned short* wp = WS + (l * 4096 + ntb * 512 + lane * 8);
      f32x4 acc[4];
      #pragma unroll
      for (int t = 0; t < 4; ++t) {
        short8 bfr = *(const short8*)(wp + t * 512);
        f32x4 zz = {0.f, 0.f, 0.f, 0.f};
        acc[t] = __builtin_amdgcn_mfma_f32_16x16x32_bf16(af, bfr, zz, 0, 0, 0);
      }
      #pragma unroll
      for (int t = 0; t < 4; ++t) {
        int n = 16 * (ntb + t) + lr;
        float bias = (ntb + t < 4) ? EB1[l * 64 + n] : 0.f;
        #pragma unroll
        for (int r = 0; r < 4; ++r) {
          int orow = 16 * rt + 4 * lg + r;
          if (orow < 29) spp[orow * 132 + n] = acc[t][r] + bias;
        }
      }
    }
    // serial layernorm: wave 3, lanes 0..28, one row each (no cross-lane ops)
    if (w == 3 && lane < 29) {
      const float* row = &sz[lane * 36];
      float s = 0.f, q = 0.f;
      #pragma unroll
      for (int c4 = 0; c4 < 6; ++c4) {        // cols 0..23 (22,23 are zero)
        float4 v = *(const float4*)(row + 4 * c4);
        s += v.x + v.y + v.z + v.w;
        q += v.x * v.x + v.y * v.y + v.z * v.z + v.w * v.w;
      }
      float mu = s * (1.f / 22.f);
      float var = q * (1.f / 22.f) - mu * mu;
      float rr = rsqrtf(var + 1e-5f);
      #pragma unroll
      for (int d = 0; d < 22; ++d)
        sin_[lane * 100 + d] = (row[d] - mu) * rr * LNG[l * 22 + d] + LNB[l * 22 + d];
    }
    __syncthreads();

    // ---- region 2: edge phase (53 tiles of 16 edges)
    {
      short8 w2f[2][4];
      #pragma unroll
      for (int s = 0; s < 2; ++s)
        #pragma unroll
        for (int t = 0; t < 4; ++t) {
          w2f[s][t] = *(const short8*)(sww + s * 2048 + t * 512 + lane * 8);
          asm volatile("" : "+v"(w2f[s][t]));   // pin: remat (if any) is a ds_read
        }
      float eb2c[4], gwc[4];
      #pragma unroll
      for (int t = 0; t < 4; ++t) {
        eb2c[t] = EB2[l * 64 + 16 * t + lr];
        gwc[t]  = GW [l * 64 + 16 * t + lr];
      }
      float gbv = GB[l];
      asm volatile("" : "+v"(eb2c[0]), "+v"(eb2c[1]), "+v"(eb2c[2]), "+v"(eb2c[3]),
                         "+v"(gwc[0]), "+v"(gwc[1]), "+v"(gwc[2]), "+v"(gwc[3]));

      for (int t = w; t < 53; t += 4) {
        int ec = min(t * 16 + lr, 840);
        int ia = (int)((unsigned)ec / 29u);
        int ja = ec - ia * 29;
        const float* pbase = &spp[ia * 132 + kb];
        const float* qbase = &spp[ja * 132 + 64 + kb];
        short8 af[2];
        #pragma unroll
        for (int s = 0; s < 2; ++s) {
          float4 p0 = *(const float4*)(pbase + 32 * s);
          float4 p1 = *(const float4*)(pbase + 32 * s + 4);
          float4 q0 = *(const float4*)(qbase + 32 * s);
          float4 q1 = *(const float4*)(qbase + 32 * s + 4);
          float m1[8];
          m1[0] = fsilu(p0.x + q0.x);
          m1[1] = fsilu(p0.y + q0.y);
          m1[2] = fsilu(p0.z + q0.z);
          m1[3] = fsilu(p0.w + q0.w);
          m1[4] = fsilu(p1.x + q1.x);
          m1[5] = fsilu(p1.y + q1.y);
          m1[6] = fsilu(p1.z + q1.z);
          m1[7] = fsilu(p1.w + q1.w);
          af[s] = pack8(m1);
        }
        f32x4 acc0 = {0.f,0.f,0.f,0.f}, acc1 = {0.f,0.f,0.f,0.f};
        f32x4 acc2 = {0.f,0.f,0.f,0.f}, acc3 = {0.f,0.f,0.f,0.f};
        #pragma unroll
        for (int s = 0; s < 2; ++s) {
          acc0 = __builtin_amdgcn_mfma_f32_16x16x32_bf16(af[s], w2f[s][0], acc0, 0, 0, 0);
          acc1 = __builtin_amdgcn_mfma_f32_16x16x32_bf16(af[s], w2f[s][1], acc1, 0, 0, 0);
          acc2 = __builtin_amdgcn_mfma_f32_16x16x32_bf16(af[s], w2f[s][2], acc2, 0, 0, 0);
          acc3 = __builtin_amdgcn_mfma_f32_16x16x32_bf16(af[s], w2f[s][3], acc3, 0, 0, 0);
        }
        float m2v[4][4];
        #pragma unroll
        for (int r = 0; r < 4; ++r) {
          m2v[0][r] = fsilu(acc0[r] + eb2c[0]);
          m2v[1][r] = fsilu(acc1[r] + eb2c[1]);
          m2v[2][r] = fsilu(acc2[r] + eb2c[2]);
          m2v[3][r] = fsilu(acc3[r] + eb2c[3]);
        }
        float g0 = m2v[0][0]*gwc[0] + m2v[1][0]*gwc[1] + m2v[2][0]*gwc[2] + m2v[3][0]*gwc[3];
        float g1 = m2v[0][1]*gwc[0] + m2v[1][1]*gwc[1] + m2v[2][1]*gwc[2] + m2v[3][1]*gwc[3];
        float g2 = m2v[0][2]*gwc[0] + m2v[1][2]*gwc[1] + m2v[2][2]*gwc[2] + m2v[3][2]*gwc[3];
        float g3 = m2v[0][3]*gwc[0] + m2v[1][3]*gwc[1] + m2v[2][3]*gwc[2] + m2v[3][3]*gwc[3];
        g0 = row16_sum(g0);            // DPP rotation-reduce over the 16-lane row
        g1 = row16_sum(g1);
        g2 = row16_sum(g2);
        g3 = row16_sum(g3);
        float gv[4];
        {
          float gg[4] = {g0, g1, g2, g3};
          #pragma unroll
          for (int r = 0; r < 4; ++r) {
            int er = t * 16 + 4 * lg + r;
            gv[r] = (er < 841) ? fsigmoid(gg[r] + gbv) : 0.f;
          }
        }
        #pragma unroll
        for (int r = 0; r < 4; ++r) {
          int er = min(t * 16 + 4 * lg + r, 840);
          int ir = (int)((unsigned)er / 29u);
          float* dst = &sin_[ir * 100 + 22 + lr];
          unsafeAtomicAdd(dst +  0, m2v[0][r] * gv[r]);
          unsafeAtomicAdd(dst + 16, m2v[1][r] * gv[r]);
          unsafeAtomicAdd(dst + 32, m2v[2][r] * gv[r]);
          unsafeAtomicAdd(dst + 48, m2v[3][r] * gv[r]);
        }
      }
    }
    __syncthreads();

    // ---- phase C: h1 = silu(bf16([zn|macc]) @ NW1F + nb1) -> sh1
    {
      int rt = w >> 1;
      int ntb = 2 * (w & 1);
      int rowc = min(16 * rt + lr, 28);
      const unsigned short* wp = WS + (16384 + l * 6144 + ntb * 512 + lane * 8);
      f32x4 acc[2] = {{0.f,0.f,0.f,0.f}, {0.f,0.f,0.f,0.f}};
      #pragma unroll
      for (int s = 0; s < 3; ++s) {
        float ar[8];
        *(float4*)&ar[0] = *(const float4*)&sin_[rowc * 100 + kb + 32 * s];
        *(float4*)&ar[4] = *(const float4*)&sin_[rowc * 100 + kb + 32 * s + 4];
        short8 af = pack8(ar);
        #pragma unroll
        for (int t = 0; t < 2; ++t) {
          short8 bfr = *(const short8*)(wp + s * 2048 + t * 512);
          acc[t] = __builtin_amdgcn_mfma_f32_16x16x32_bf16(af, bfr, acc[t], 0, 0, 0);
        }
      }
      #pragma unroll
      for (int t = 0; t < 2; ++t) {
        int n = 16 * (ntb + t) + lr;
        float bias = NB1[l * 64 + n];
        #pragma unroll
        for (int r = 0; r < 4; ++r) {
          int orow = 16 * rt + 4 * lg + r;
          if (orow < 29) sh1[orow * 68 + n] = fsilu(acc[t][r] + bias);
        }
      }
    }
    __syncthreads();

    // ---- phase D: z += bf16(h1) @ NW2F + nb2
    {
      int rt = w & 1;
      int nt = w >> 1;
      int rowc = min(16 * rt + lr, 28);
      int d = 16 * nt + lr;
      const unsigned short* wp = WS + (28672 + l * 2048 + nt * 512 + lane * 8);
      f32x4 acc = {0.f, 0.f, 0.f, 0.f};
      #pragma unroll
      for (int s = 0; s < 2; ++s) {
        float ar[8];
        *(float4*)&ar[0] = *(const float4*)&sh1[rowc * 68 + kb + 32 * s];
        *(float4*)&ar[4] = *(const float4*)&sh1[rowc * 68 + kb + 32 * s + 4];
        short8 af = pack8(ar);
        short8 bfr = *(const short8*)(wp + s * 1024);
        acc = __builtin_amdgcn_mfma_f32_16x16x32_bf16(af, bfr, acc, 0, 0, 0);
      }
      float bias = (d < 22) ? NB2[l * 22 + d] : 0.f;
      #pragma unroll
      for (int r = 0; r < 4; ++r) {
        int orow = 16 * rt + 4 * lg + r;
        if (orow < 29 && d < 22) sz[orow * 36 + d] += acc[r] + bias;
      }
    }
    __syncthreads();
  }

  // ---- head: mean pool, relu MLP, padded write
  if (tid < 22) {
    float s = 0.f;
    #pragma unroll
    for (int i = 0; i < 29; ++i) s += sz[i * 36 + tid];
    szm[tid] = s * (1.f / 29.f);
  }
  __syncthreads();
  if (tid < 64) {
    float a = HB1[tid];
    #pragma unroll
    for (int d = 0; d < 22; ++d) a += szm[d] * HW1[d * 64 + tid];
    shh[tid] = fmaxf(a, 0.f);
  }
  __syncthreads();
  if (tid < 24) {
    float a = HB2[tid];
    #pragma unroll
    for (int m = 0; m < 64; ++m) a += shh[m] * HW2[m * 24 + tid];
    sob[tid] = a;
  }
  __syncthreads();
  for (int t = tid; t < 29 * 12; t += TPB) {
    OUTP[b * 348 + t] = (t < 24) ? sob[t] : 0.f;
  }
}

extern "C" void kernel_launch(void* const* d_in, const int* in_sizes, int n_in,
                              void* d_out, int out_size, void* d_ws, size_t ws_size,
                              hipStream_t stream) {
  const float* X   = (const float*)d_in[0];
  const float* CTX = (const float*)d_in[1];
  const float* EW1 = (const float*)d_in[2];
  const float* EB1 = (const float*)d_in[3];
  const float* EW2 = (const float*)d_in[4];
  const float* EB2 = (const float*)d_in[5];
  const float* GW  = (const float*)d_in[6];
  const float* GB  = (const float*)d_in[7];
  const float* LNG = (const float*)d_in[8];
  const float* LNB = (const float*)d_in[9];
  const float* NW1 = (const float*)d_in[10];
  const float* NB1 = (const float*)d_in[11];
  const float* NW2 = (const float*)d_in[12];
  const float* NB2 = (const float*)d_in[13];
  const float* HW1 = (const float*)d_in[14];
  const float* HB1 = (const float*)d_in[15];
  const float* HW2 = (const float*)d_in[16];
  const float* HB2 = (const float*)d_in[17];
  float* OUTP = (float*)d_out;
  unsigned short* WS = (unsigned short*)d_ws;  // 32768 bf16 = 64 KB

  hipLaunchKernelGGL(setup_kernel, dim3(128), dim3(256), 0, stream,
                     EW1, EW2, NW1, NW2, WS);
  hipLaunchKernelGGL(gnn_kernel, dim3(4096), dim3(TPB), 0, stream,
                     X, CTX, EB1, EB2, GW, GB, LNG, LNB, NB1, NB2,
                     HW1, HB1, HW2, HB2, WS, OUTP);
}

// Round 5
// 389.755 us; speedup vs baseline: 11.2838x; 6.0174x over previous
//
#include <hip/hip_runtime.h>
#include <hip/hip_bf16.h>

typedef __attribute__((ext_vector_type(8))) short short8;
typedef __attribute__((ext_vector_type(4))) float f32x4;

__device__ __forceinline__ float fsigmoid(float x) {
  return __builtin_amdgcn_rcpf(1.0f + __expf(-x));
}
__device__ __forceinline__ float fsilu(float x) { return x * fsigmoid(x); }
__device__ __forceinline__ unsigned short bf16b(float x) {
  union { float f; unsigned u; } c; c.f = x;
  unsigned r = c.u + 0x7FFFu + ((c.u >> 16) & 1u);
  return (unsigned short)(r >> 16);
}
__device__ __forceinline__ float b2f(unsigned short u) {
  union { unsigned v; float f; } c; c.v = ((unsigned)u) << 16; return c.f;
}
__device__ __forceinline__ short8 pack8(const float* v) {
  short8 r;
  #pragma unroll
  for (int m = 0; m < 4; ++m) {
    __hip_bfloat162 h = __float22bfloat162_rn(make_float2(v[2 * m], v[2 * m + 1]));
    short2 s2 = *reinterpret_cast<const short2*>(&h);
    r[2 * m] = s2.x; r[2 * m + 1] = s2.y;
  }
  return r;
}
template<int CTRL>
__device__ __forceinline__ float dpp_add(float x) {
  int xi = __builtin_bit_cast(int, x);
  int yi = __builtin_amdgcn_update_dpp(0, xi, CTRL, 0xF, 0xF, true);
  return x + __builtin_bit_cast(float, yi);
}
__device__ __forceinline__ float row16_sum(float x) {
  x = dpp_add<0x121>(x);
  x = dpp_add<0x122>(x);
  x = dpp_add<0x124>(x);
  x = dpp_add<0x128>(x);
  return x;
}

// ---- setup: bf16 B-fragments for all 4 GEMMs (layout unchanged from R2-R4) ----
__global__ void setup_kernel(const float* __restrict__ eW1, const float* __restrict__ eW2,
                             const float* __restrict__ nW1, const float* __restrict__ nW2,
                             unsigned short* __restrict__ WS) {
  int t = blockIdx.x * 256 + threadIdx.x;
  float val = 0.f;
  if (t < 8192) {                       // EW1F
    int l = t >> 12, r = t & 4095;
    int nt = r >> 9, lane = (r >> 3) & 63, e = r & 7;
    int k = 8 * (lane >> 4) + e, n = 16 * nt + (lane & 15);
    if (k < 22) val = (n < 64) ? eW1[l * 2816 + k * 64 + n]
                               : eW1[l * 2816 + (22 + k) * 64 + (n - 64)];
  } else if (t < 16384) {               // EW2F
    int u = t - 8192;
    int l = u >> 12, r = u & 4095;
    int ks = r >> 11, nt = (r >> 9) & 3, lane = (r >> 3) & 63, e = r & 7;
    int k = 32 * ks + 8 * (lane >> 4) + e, n = 16 * nt + (lane & 15);
    val = eW2[l * 4096 + k * 64 + n];
  } else if (t < 28672) {               // NW1F
    int u = t - 16384;
    int l = u / 6144, r = u % 6144;
    int ks = r >> 11, nt = (r >> 9) & 3, lane = (r >> 3) & 63, e = r & 7;
    int k = 32 * ks + 8 * (lane >> 4) + e, n = 16 * nt + (lane & 15);
    if (k < 86) val = nW1[l * 5504 + k * 64 + n];
  } else {                              // NW2F
    int u = t - 28672;
    int l = u >> 11, r = u & 2047;
    int ks = r >> 10, nt = (r >> 9) & 1, lane = (r >> 3) & 63, e = r & 7;
    int k = 32 * ks + 8 * (lane >> 4) + e, n = 16 * nt + (lane & 15);
    if (n < 22) val = nW2[l * 1408 + k * 22 + n];
  }
  WS[t] = bf16b(val);
}

// ---- K1: z -> pi|pj projections (SPP bf16) + layernorm (CIN[:,0:22] bf16) ----
__launch_bounds__(256, 4)
__global__ void proj_kernel(const float* __restrict__ X, const float* __restrict__ CTX,
                            const unsigned short* __restrict__ WS,
                            const float* __restrict__ EB1,
                            const float* __restrict__ LNG, const float* __restrict__ LNB,
                            float* __restrict__ Z, unsigned short* __restrict__ SPP,
                            unsigned short* __restrict__ CIN, int l)
{
  __shared__ float sz[29 * 36];
  const int b = blockIdx.x, tid = threadIdx.x;
  const int lane = tid & 63, w = tid >> 6;
  const int lr = lane & 15, lg = lane >> 4, kb = lg * 8;

  if (l == 0) {
    for (int t = tid; t < 29 * 36; t += 256) {
      int i = t / 36, c = t - i * 36;
      float v = 0.f;
      if (c < 6) v = X[b * 174 + i * 6 + c];
      else if (c < 22) v = CTX[b * 464 + i * 16 + (c - 6)];
      sz[t] = v;
      if (c < 32) Z[(b * 29 + i) * 32 + c] = v;
    }
  } else {
    for (int t = tid; t < 29 * 36; t += 256) {
      int i = t / 36, c = t - i * 36;
      sz[t] = (c < 32) ? Z[(b * 29 + i) * 32 + c] : 0.f;
    }
  }
  __syncthreads();

  // projections: spp = bf16(z) @ EW1F (+eb1 on pi half)
  {
    int rt = w >> 1;
    int rowc = min(16 * rt + lr, 28);
    float zr[8];
    *(float4*)&zr[0] = *(const float4*)&sz[rowc * 36 + kb];
    *(float4*)&zr[4] = *(const float4*)&sz[rowc * 36 + kb + 4];
    short8 af = pack8(zr);
    int ntb = 4 * (w & 1);
    const unsigned short* wp = WS + (l * 4096 + ntb * 512 + lane * 8);
    #pragma unroll
    for (int t = 0; t < 4; ++t) {
      short8 bfr = *(const short8*)(wp + t * 512);
      f32x4 zz = {0.f, 0.f, 0.f, 0.f};
      f32x4 acc = __builtin_amdgcn_mfma_f32_16x16x32_bf16(af, bfr, zz, 0, 0, 0);
      int n = 16 * (ntb + t) + lr;
      float bias = (ntb + t < 4) ? EB1[l * 64 + n] : 0.f;
      #pragma unroll
      for (int r = 0; r < 4; ++r) {
        int orow = 16 * rt + 4 * lg + r;
        if (orow < 29) SPP[(b * 29 + orow) * 128 + n] = bf16b(acc[r] + bias);
      }
    }
  }
  // layernorm: wave 3, lanes 0..28, one row each -> CIN[:, 0:22]; zero pad 86..95
  if (w == 3 && lane < 29) {
    const float* row = &sz[lane * 36];
    float s = 0.f, q = 0.f;
    #pragma unroll
    for (int c4 = 0; c4 < 6; ++c4) {
      float4 v = *(const float4*)(row + 4 * c4);
      s += v.x + v.y + v.z + v.w;
      q += v.x * v.x + v.y * v.y + v.z * v.z + v.w * v.w;
    }
    float mu = s * (1.f / 22.f);
    float var = q * (1.f / 22.f) - mu * mu;
    float rr = rsqrtf(var + 1e-5f);
    unsigned short* crow = CIN + (b * 29 + lane) * 96;
    #pragma unroll
    for (int d = 0; d < 22; ++d)
      crow[d] = bf16b((row[d] - mu) * rr * LNG[l * 22 + d] + LNB[l * 22 + d]);
    #pragma unroll
    for (int d = 86; d < 96; ++d) crow[d] = 0;
  }
}

// ---- K2: edge phase. One wave per (b,i): 2 j-tiles of 16, register aggregation,
//      no LDS, no barriers, no atomics. grid = 4096*29/4 blocks ----
__launch_bounds__(256, 2)
__global__ void edge_kernel(const unsigned short* __restrict__ WS,
                            const unsigned short* __restrict__ SPP,
                            const float* __restrict__ EB2, const float* __restrict__ GW,
                            const float* __restrict__ GB,
                            unsigned short* __restrict__ CIN, int l)
{
  const int tid = threadIdx.x;
  const int lane = tid & 63, w = tid >> 6;
  const int lr = lane & 15, lg = lane >> 4, kb = lg * 8;
  const int wid = blockIdx.x * 4 + w;          // < 4096*29 exactly
  const int b = (int)((unsigned)wid / 29u);
  const int i = wid - b * 29;

  // weights (L2-resident)
  const unsigned short* wp = WS + (8192 + l * 4096 + lane * 8);
  short8 w2f[2][4];
  #pragma unroll
  for (int s = 0; s < 2; ++s)
    #pragma unroll
    for (int t = 0; t < 4; ++t)
      w2f[s][t] = *(const short8*)(wp + s * 2048 + t * 512);
  float eb2c[4], gwc[4];
  #pragma unroll
  for (int t = 0; t < 4; ++t) {
    eb2c[t] = EB2[l * 64 + 16 * t + lr];
    gwc[t]  = GW [l * 64 + 16 * t + lr];
  }
  const float gbv = GB[l];

  // pi slice for row i (uniform per lane-group), both k-steps
  const unsigned short* pirow = SPP + (b * 29 + i) * 128 + kb;
  short8 pib0 = *(const short8*)(pirow);
  short8 pib1 = *(const short8*)(pirow + 32);
  float pif[2][8];
  #pragma unroll
  for (int m = 0; m < 8; ++m) { pif[0][m] = b2f(pib0[m]); pif[1][m] = b2f(pib1[m]); }

  float macc[4] = {0.f, 0.f, 0.f, 0.f};

  #pragma unroll
  for (int tb = 0; tb < 2; ++tb) {
    const int jb = tb * 16;
    const int ja = min(jb + lr, 28);
    const unsigned short* pjrow = SPP + (b * 29 + ja) * 128 + 64 + kb;
    short8 pjb0 = *(const short8*)(pjrow);
    short8 pjb1 = *(const short8*)(pjrow + 32);
    float m1[8];
    #pragma unroll
    for (int m = 0; m < 8; ++m) m1[m] = fsilu(pif[0][m] + b2f(pjb0[m]));
    short8 af0 = pack8(m1);
    #pragma unroll
    for (int m = 0; m < 8; ++m) m1[m] = fsilu(pif[1][m] + b2f(pjb1[m]));
    short8 af1 = pack8(m1);

    f32x4 a0 = {0.f,0.f,0.f,0.f}, a1 = {0.f,0.f,0.f,0.f};
    f32x4 a2 = {0.f,0.f,0.f,0.f}, a3 = {0.f,0.f,0.f,0.f};
    a0 = __builtin_amdgcn_mfma_f32_16x16x32_bf16(af0, w2f[0][0], a0, 0, 0, 0);
    a1 = __builtin_amdgcn_mfma_f32_16x16x32_bf16(af0, w2f[0][1], a1, 0, 0, 0);
    a2 = __builtin_amdgcn_mfma_f32_16x16x32_bf16(af0, w2f[0][2], a2, 0, 0, 0);
    a3 = __builtin_amdgcn_mfma_f32_16x16x32_bf16(af0, w2f[0][3], a3, 0, 0, 0);
    a0 = __builtin_amdgcn_mfma_f32_16x16x32_bf16(af1, w2f[1][0], a0, 0, 0, 0);
    a1 = __builtin_amdgcn_mfma_f32_16x16x32_bf16(af1, w2f[1][1], a1, 0, 0, 0);
    a2 = __builtin_amdgcn_mfma_f32_16x16x32_bf16(af1, w2f[1][2], a2, 0, 0, 0);
    a3 = __builtin_amdgcn_mfma_f32_16x16x32_bf16(af1, w2f[1][3], a3, 0, 0, 0);

    float m2v[4][4];
    #pragma unroll
    for (int r = 0; r < 4; ++r) {
      m2v[0][r] = fsilu(a0[r] + eb2c[0]);
      m2v[1][r] = fsilu(a1[r] + eb2c[1]);
      m2v[2][r] = fsilu(a2[r] + eb2c[2]);
      m2v[3][r] = fsilu(a3[r] + eb2c[3]);
    }
    float g0 = m2v[0][0]*gwc[0] + m2v[1][0]*gwc[1] + m2v[2][0]*gwc[2] + m2v[3][0]*gwc[3];
    float g1 = m2v[0][1]*gwc[0] + m2v[1][1]*gwc[1] + m2v[2][1]*gwc[2] + m2v[3][1]*gwc[3];
    float g2 = m2v[0][2]*gwc[0] + m2v[1][2]*gwc[1] + m2v[2][2]*gwc[2] + m2v[3][2]*gwc[3];
    float g3 = m2v[0][3]*gwc[0] + m2v[1][3]*gwc[1] + m2v[2][3]*gwc[2] + m2v[3][3]*gwc[3];
    g0 = row16_sum(g0); g1 = row16_sum(g1); g2 = row16_sum(g2); g3 = row16_sum(g3);
    float gg[4] = {g0, g1, g2, g3};
    #pragma unroll
    for (int r = 0; r < 4; ++r) {
      int jrow = jb + 4 * lg + r;
      float gv = (jrow < 29) ? fsigmoid(gg[r] + gbv) : 0.f;
      macc[0] += m2v[0][r] * gv;
      macc[1] += m2v[1][r] * gv;
      macc[2] += m2v[2][r] * gv;
      macc[3] += m2v[3][r] * gv;
    }
  }

  // cross-lane-group reduce (lanes l, l^16, l^32, l^48) and one coalesced store
  float red0 = macc[0], red1 = macc[1], red2 = macc[2], red3 = macc[3];
  red0 += __shfl_xor(red0, 16, 64); red0 += __shfl_xor(red0, 32, 64);
  red1 += __shfl_xor(red1, 16, 64); red1 += __shfl_xor(red1, 32, 64);
  red2 += __shfl_xor(red2, 16, 64); red2 += __shfl_xor(red2, 32, 64);
  red3 += __shfl_xor(red3, 16, 64); red3 += __shfl_xor(red3, 32, 64);
  float vs = (lg == 0) ? red0 : (lg == 1) ? red1 : (lg == 2) ? red2 : red3;
  CIN[(b * 29 + i) * 96 + 22 + lane] = bf16b(vs);   // k = lane, consecutive
}

// ---- K3: node MLP + residual (+ head when l==1) ----
__launch_bounds__(256, 4)
__global__ void node_kernel(const unsigned short* __restrict__ WS,
                            const unsigned short* __restrict__ CIN,
                            const float* __restrict__ NB1, const float* __restrict__ NB2,
                            float* __restrict__ Z,
                            const float* __restrict__ HW1, const float* __restrict__ HB1,
                            const float* __restrict__ HW2, const float* __restrict__ HB2,
                            float* __restrict__ OUTP, int l)
{
  __shared__ float sz[29 * 32];
  __shared__ float sh1[29 * 68];
  __shared__ float szm[22], shh[64], sob[24];
  const int b = blockIdx.x, tid = threadIdx.x;
  const int lane = tid & 63, w = tid >> 6;
  const int lr = lane & 15, lg = lane >> 4, kb = lg * 8;

  for (int t = tid; t < 29 * 8; t += 256)
    ((float4*)sz)[t] = ((const float4*)(Z + b * 29 * 32))[t];
  __syncthreads();

  // h1 = silu(bf16([zn|macc]) @ NW1F + nb1): A read straight from CIN (already bf16)
  {
    int rt = w >> 1;
    int ntb = 2 * (w & 1);
    int rowc = min(16 * rt + lr, 28);
    const unsigned short* arow = CIN + (b * 29 + rowc) * 96 + kb;
    const unsigned short* wp = WS + (16384 + l * 6144 + ntb * 512 + lane * 8);
    f32x4 acc[2] = {{0.f,0.f,0.f,0.f}, {0.f,0.f,0.f,0.f}};
    #pragma unroll
    for (int s = 0; s < 3; ++s) {
      short8 af = *(const short8*)(arow + 32 * s);
      #pragma unroll
      for (int t = 0; t < 2; ++t) {
        short8 bfr = *(const short8*)(wp + s * 2048 + t * 512);
        acc[t] = __builtin_amdgcn_mfma_f32_16x16x32_bf16(af, bfr, acc[t], 0, 0, 0);
      }
    }
    #pragma unroll
    for (int t = 0; t < 2; ++t) {
      int n = 16 * (ntb + t) + lr;
      float bias = NB1[l * 64 + n];
      #pragma unroll
      for (int r = 0; r < 4; ++r) {
        int orow = 16 * rt + 4 * lg + r;
        if (orow < 29) sh1[orow * 68 + n] = fsilu(acc[t][r] + bias);
      }
    }
  }
  __syncthreads();

  // z += bf16(h1) @ NW2F + nb2
  {
    int rt = w & 1;
    int nt = w >> 1;
    int rowc = min(16 * rt + lr, 28);
    int d = 16 * nt + lr;
    const unsigned short* wp = WS + (28672 + l * 2048 + nt * 512 + lane * 8);
    f32x4 acc = {0.f, 0.f, 0.f, 0.f};
    #pragma unroll
    for (int s = 0; s < 2; ++s) {
      float ar[8];
      *(float4*)&ar[0] = *(const float4*)&sh1[rowc * 68 + kb + 32 * s];
      *(float4*)&ar[4] = *(const float4*)&sh1[rowc * 68 + kb + 32 * s + 4];
      short8 af = pack8(ar);
      short8 bfr = *(const short8*)(wp + s * 1024);
      acc = __builtin_amdgcn_mfma_f32_16x16x32_bf16(af, bfr, acc, 0, 0, 0);
    }
    float bias = (d < 22) ? NB2[l * 22 + d] : 0.f;
    #pragma unroll
    for (int r = 0; r < 4; ++r) {
      int orow = 16 * rt + 4 * lg + r;
      if (orow < 29 && d < 22) sz[orow * 32 + d] += acc[r] + bias;
    }
  }
  __syncthreads();

  if (l == 0) {
    for (int t = tid; t < 29 * 8; t += 256)
      ((float4*)(Z + b * 29 * 32))[t] = ((const float4*)sz)[t];
  } else {
    // head: mean pool, relu MLP, padded write
    if (tid < 22) {
      float s = 0.f;
      #pragma unroll
      for (int i = 0; i < 29; ++i) s += sz[i * 32 + tid];
      szm[tid] = s * (1.f / 29.f);
    }
    __syncthreads();
    if (tid < 64) {
      float a = HB1[tid];
      #pragma unroll
      for (int d = 0; d < 22; ++d) a += szm[d] * HW1[d * 64 + tid];
      shh[tid] = fmaxf(a, 0.f);
    }
    __syncthreads();
    if (tid < 24) {
      float a = HB2[tid];
      #pragma unroll
      for (int m = 0; m < 64; ++m) a += shh[m] * HW2[m * 24 + tid];
      sob[tid] = a;
    }
    __syncthreads();
    for (int t = tid; t < 29 * 12; t += 256)
      OUTP[b * 348 + t] = (t < 24) ? sob[t] : 0.f;
  }
}

extern "C" void kernel_launch(void* const* d_in, const int* in_sizes, int n_in,
                              void* d_out, int out_size, void* d_ws, size_t ws_size,
                              hipStream_t stream) {
  const float* X   = (const float*)d_in[0];
  const float* CTX = (const float*)d_in[1];
  const float* EW1 = (const float*)d_in[2];
  const float* EB1 = (const float*)d_in[3];
  const float* EW2 = (const float*)d_in[4];
  const float* EB2 = (const float*)d_in[5];
  const float* GW  = (const float*)d_in[6];
  const float* GB  = (const float*)d_in[7];
  const float* LNG = (const float*)d_in[8];
  const float* LNB = (const float*)d_in[9];
  const float* NW1 = (const float*)d_in[10];
  const float* NB1 = (const float*)d_in[11];
  const float* NW2 = (const float*)d_in[12];
  const float* NB2 = (const float*)d_in[13];
  const float* HW1 = (const float*)d_in[14];
  const float* HB1 = (const float*)d_in[15];
  const float* HW2 = (const float*)d_in[16];
  const float* HB2 = (const float*)d_in[17];
  float* OUTP = (float*)d_out;

  // workspace layout: WS fragments 64KB | Z f32 15.2MB | SPP bf16 30.4MB | CIN bf16 22.8MB
  unsigned short* WS = (unsigned short*)d_ws;
  float* Z = (float*)((char*)d_ws + 65536);
  unsigned short* SPP = (unsigned short*)((char*)d_ws + 65536 + 15204352);
  unsigned short* CIN = (unsigned short*)((char*)d_ws + 65536 + 15204352 + 30408704);

  hipLaunchKernelGGL(setup_kernel, dim3(128), dim3(256), 0, stream,
                     EW1, EW2, NW1, NW2, WS);
  for (int l = 0; l < 2; ++l) {
    hipLaunchKernelGGL(proj_kernel, dim3(4096), dim3(256), 0, stream,
                       X, CTX, WS, EB1, LNG, LNB, Z, SPP, CIN, l);
    hipLaunchKernelGGL(edge_kernel, dim3(4096 * 29 / 4), dim3(256), 0, stream,
                       WS, SPP, EB2, GW, GB, CIN, l);
    hipLaunchKernelGGL(node_kernel, dim3(4096), dim3(256), 0, stream,
                       WS, CIN, NB1, NB2, Z, HW1, HB1, HW2, HB2, OUTP, l);
  }
}